// Round 7
// baseline (282.231 us; speedup 1.0000x reference)
//
#include <hip/hip_runtime.h>
#include <math.h>

namespace {
constexpr int D = 256;
constexpr int H = 8;
constexpr int HD = 32;
constexpr int B = 8;
constexpr int S = 127;
constexpr int N = 128;
constexpr float LN_EPS = 1e-5f;

// ws layout (float offsets). P1T/P2T are stored PACKED:
// element (b, c, i) at (b*64 + (c>>2))*512 + i*4 + (c&3)  -> float4 over c for fixed i.
// P1T rows INCLUDE eb1 (folded at kA time).
constexpr int WS_P1T = 0;                  // B*D*N
constexpr int WS_P2T = WS_P1T + B * D * N; // B*D*N
constexpr int WS_V   = WS_P2T + B * D * N; // B*N*D (row-major)
constexpr int WS_AQ  = WS_V + B * N * D;   // B*H*N
constexpr int WS_AK  = WS_AQ + B * H * N;  // B*H*N
constexpr int WS_FQK = WS_AK + B * H * N;  // D*16 (wq-fold | wk-fold)
constexpr int WS_V2  = WS_FQK + D * 16;    // H*D (transposed: [h][c])
constexpr int WS_BF  = WS_V2 + D * H;      // 32 (bq-fold[8], bk-fold[8], be-fold[8])
constexpr int WS_ST  = WS_BF + 32;         // B*4*N row stats: S1,Q1,S2,Q2 (incl eb1 in P1)
constexpr int WS_RSTD = WS_ST + B * 512;   // B*N*N per-pair 1/std
constexpr int WS_MB   = WS_RSTD + B * N * N; // B*N*N per-pair -mean/std

union F4 { float4 v; float f[4]; };
} // namespace

// K1: fold wq/wk with attn_w[:32]/[32:64] -> FQK (D x 16), ew2 with attn_w[64:96]
// -> V2T (H x D), plus bias folds. Thread-per-output.
__global__ __launch_bounds__(256) void k1_fold(
    const float* __restrict__ wq, const float* __restrict__ wk,
    const float* __restrict__ ew2, const float* __restrict__ bq,
    const float* __restrict__ bk, const float* __restrict__ eb2,
    const float* __restrict__ attn_w, float* __restrict__ ws) {
  float* FQK = ws + WS_FQK;
  float* V2T = ws + WS_V2;
  float* BF  = ws + WS_BF;
  const int tg = blockIdx.x * 256 + threadIdx.x;
  if (tg < 6144) {
    const int mat = tg >> 11;
    const int rem = tg & 2047;
    const int c = rem >> 3;
    const int h = rem & 7;
    const float* W = (mat == 0) ? wq : (mat == 1) ? wk : ew2;
    const float* aw = attn_w + mat * HD;
    const float* wrow = W + c * D + h * HD;
    float s = 0.f;
#pragma unroll
    for (int d = 0; d < HD; ++d) s = fmaf(wrow[d], aw[d], s);
    if (mat < 2) FQK[c * 16 + mat * 8 + h] = s;
    else         V2T[h * D + c] = s;
  } else if (tg < 6168) {
    const int idx = tg - 6144;
    const int mat = idx >> 3;
    const int h = idx & 7;
    const float* bias = (mat == 0) ? bq : (mat == 1) ? bk : eb2;
    const float* aw = attn_w + mat * HD;
    float s = 0.f;
#pragma unroll
    for (int d = 0; d < HD; ++d) s = fmaf(bias[h * HD + d], aw[d], s);
    BF[mat * 8 + h] = s;
  }
}

// KA: role 0 (blocks 0..255): P1/P2 packed-transposed (+eb1 into P1) and the
// per-row stats S1,Q1,S2,Q2. role 1 (blocks 256..511): V rows + aq/ak.
__global__ __launch_bounds__(256) void kA_pre(
    const float* __restrict__ desc, const float* __restrict__ ew1,
    const float* __restrict__ eb1,
    const float* __restrict__ nv, const float* __restrict__ wv,
    const float* __restrict__ bv, float* __restrict__ ws) {
  const int blk = blockIdx.x;
  const int t = threadIdx.x;
  __shared__ float rows[4][264];
  __shared__ float aqred[4][64];
  __shared__ float statred[4][16];

  if (blk < 256) {
    // ---- role 0 ----
    float* P1Tf = ws + WS_P1T;
    float* P2Tf = ws + WS_P2T;
    const int b = blk >> 5;
    const int i0 = (blk & 31) * 4;
    for (int k = t; k < 4 * D; k += 256) {
      const int r = k >> 8, c = k & (D - 1);
      const int row = i0 + r;
      rows[r][c] = (row < S) ? desc[(b * S + row) * D + c] : 0.f;
    }
    __syncthreads();
    float a1[4], a2[4];
#pragma unroll
    for (int ii = 0; ii < 4; ++ii) { a1[ii] = 0.f; a2[ii] = 0.f; }
    for (int c2 = 0; c2 < D; c2 += 4) {
      float w1[4], w2[4];
#pragma unroll
      for (int e = 0; e < 4; ++e) {
        w1[e] = ew1[(c2 + e) * D + t];
        w2[e] = ew1[(D + c2 + e) * D + t];
      }
#pragma unroll
      for (int ii = 0; ii < 4; ++ii) {
        F4 dv; dv.v = *(const float4*)&rows[ii][c2];
#pragma unroll
        for (int e = 0; e < 4; ++e) {
          a1[ii] = fmaf(dv.f[e], w1[e], a1[ii]);
          a2[ii] = fmaf(dv.f[e], w2[e], a2[ii]);
        }
      }
    }
    const float ebv = eb1[t];
    const int pbase = (b * 64 + (t >> 2)) * 512 + (t & 3);
#pragma unroll
    for (int ii = 0; ii < 4; ++ii) {
      if (i0 + ii < S) {
        P1Tf[pbase + (i0 + ii) * 4] = a1[ii] + ebv;
        P2Tf[pbase + (i0 + ii) * 4] = a2[ii];
      }
    }
    // per-row stats (S1,Q1 of p1+eb1; S2,Q2 of p2), reduced over channels
    float stv[16];
#pragma unroll
    for (int ii = 0; ii < 4; ++ii) {
      const float v1 = a1[ii] + ebv;
      const float v2x = a2[ii];
      stv[ii * 4 + 0] = v1;
      stv[ii * 4 + 1] = v1 * v1;
      stv[ii * 4 + 2] = v2x;
      stv[ii * 4 + 3] = v2x * v2x;
    }
#pragma unroll
    for (int st = 0; st < 16; ++st) {
#pragma unroll
      for (int o = 1; o < 64; o <<= 1) stv[st] += __shfl_xor(stv[st], o);
    }
    const int w = t >> 6;
    if ((t & 63) == 0) {
#pragma unroll
      for (int st = 0; st < 16; ++st) statred[w][st] = stv[st];
    }
    __syncthreads();
    if (t < 16) {
      const int ii = t >> 2, st = t & 3;
      if (i0 + ii < S) {
        const float s = statred[0][t] + statred[1][t]
                      + statred[2][t] + statred[3][t];
        ws[WS_ST + b * 512 + st * 128 + (i0 + ii)] = s;
      }
    }
  } else {
    // ---- role 1: v = nv @ wv + bv, aq/ak via folded FQK ----
    float* Vf  = ws + WS_V;
    float* AQ  = ws + WS_AQ;
    float* AK  = ws + WS_AK;
    const float* FQK = ws + WS_FQK;
    const float* BF  = ws + WS_BF;
    const int blk2 = blk - 256;
    const int b = blk2 >> 5;
    const int j0 = (blk2 & 31) * 4;
    for (int k = t; k < 4 * D; k += 256) {
      const int r = k >> 8, c = k & (D - 1);
      rows[r][c] = nv[(b * N + j0 + r) * D + c];
    }
    __syncthreads();
    float acc[4];
#pragma unroll
    for (int jj = 0; jj < 4; ++jj) acc[jj] = 0.f;
    for (int c2 = 0; c2 < D; c2 += 4) {
      float wvv[4];
#pragma unroll
      for (int e = 0; e < 4; ++e) wvv[e] = wv[(c2 + e) * D + t];
#pragma unroll
      for (int jj = 0; jj < 4; ++jj) {
        F4 x; x.v = *(const float4*)&rows[jj][c2];
#pragma unroll
        for (int e = 0; e < 4; ++e) acc[jj] = fmaf(x.f[e], wvv[e], acc[jj]);
      }
    }
    const float bias = bv[t];
#pragma unroll
    for (int jj = 0; jj < 4; ++jj)
      Vf[(b * N + j0 + jj) * D + t] = acc[jj] + bias;

    const int pair = t & 63;        // (row il, output oi)
    const int cq = t >> 6;          // channel quarter
    const int il = pair >> 4, oi = pair & 15;
    float s = 0.f;
    for (int c = cq * 64; c < cq * 64 + 64; ++c)
      s = fmaf(rows[il][c], FQK[c * 16 + oi], s);
    aqred[cq][pair] = s;
    __syncthreads();
    if (t < 64) {
      const int il2 = t >> 4, oi2 = t & 15;
      float s2 = aqred[0][t] + aqred[1][t] + aqred[2][t] + aqred[3][t] + BF[oi2];
      if (oi2 < 8) AQ[(b * H + oi2) * N + j0 + il2] = s2;
      else         AK[(b * H + (oi2 - 8)) * N + j0 + il2] = s2;
    }
  }
}

// KG: G = P1 . P2 per (ip,jp) pair via reg-cached P2 slices, then fold with
// row stats ST into per-pair rstd / mB. grid 256 (XCD-swizzled), 512 threads:
// jp = t&127, cg = t>>7 (64-channel group); 4 ip rows per block.
__global__ __launch_bounds__(512) void kG_stats(float* __restrict__ ws) {
  const int bid = blockIdx.x;
  const int wg = (bid & 7) * 32 + (bid >> 3);   // one b per XCD
  const int b = wg >> 5;
  const int ip0 = (wg & 31) * 4;
  const int t = threadIdx.x;
  const int jp = t & 127;
  const int cg = t >> 7;

  __shared__ float p1t[1024];        // [4][256]
  __shared__ float gred[4][4][128];  // [cg][r][jp]

  const float* P1Tf = ws + WS_P1T;
  const float4* P24 = reinterpret_cast<const float4*>(ws + WS_P2T);
  const float* ST = ws + WS_ST + b * 512;
  float* RST = ws + WS_RSTD + b * N * N;
  float* MBP = ws + WS_MB + b * N * N;
  const int base4 = b * 64 * 128;

  for (int k = t; k < 1024; k += 512) {
    const int r = k >> 8, c = k & 255;
    const int row = ip0 + r;
    p1t[r * 256 + c] = (row < S)
        ? P1Tf[(b * 64 + (c >> 2)) * 512 + row * 4 + (c & 3)] : 0.f;
  }
  F4 pp[16];
#pragma unroll
  for (int cc = 0; cc < 16; ++cc)
    pp[cc].v = P24[base4 + (cg * 16 + cc) * 128 + jp];
  __syncthreads();

  float g[4] = {0.f, 0.f, 0.f, 0.f};
#pragma unroll
  for (int cc = 0; cc < 16; ++cc) {
    const int c4 = cg * 16 + cc;
#pragma unroll
    for (int r = 0; r < 4; ++r) {
      F4 p1; p1.v = *(const float4*)&p1t[r * 256 + c4 * 4];
      g[r] = fmaf(pp[cc].f[0], p1.f[0], g[r]);
      g[r] = fmaf(pp[cc].f[1], p1.f[1], g[r]);
      g[r] = fmaf(pp[cc].f[2], p1.f[2], g[r]);
      g[r] = fmaf(pp[cc].f[3], p1.f[3], g[r]);
    }
  }
#pragma unroll
  for (int r = 0; r < 4; ++r) gred[cg][r][jp] = g[r];
  __syncthreads();
  {
    const int r2 = t >> 7, jp2 = t & 127;
    const float G = gred[0][r2][jp2] + gred[1][r2][jp2]
                  + gred[2][r2][jp2] + gred[3][r2][jp2];
    const int ip = ip0 + r2;
    const float S1 = ST[0 * 128 + ip], Q1 = ST[1 * 128 + ip];
    const float S2 = ST[2 * 128 + jp2], Q2 = ST[3 * 128 + jp2];
    const float mean = (S1 + S2) * (1.f / 256.f);
    const float var = (Q1 + Q2 + 2.f * G) * (1.f / 256.f) - mean * mean;
    const float rstd = 1.f / sqrtf(var + LN_EPS);
    RST[ip * N + jp2] = rstd;
    MBP[ip * N + jp2] = -mean * rstd;
  }
}

// K4: edge-MLP dot + scores + softmax + attn write.
// grid 256 (XCD-swizzled): block = (b, 4-row i-tile). 1024 threads:
// jl = t&127 (column j), hg = t>>7 (32-channel group for MLP; head for softmax).
// P2 slice lives in 8 float4 REGISTERS; v2/g/b/p1 are LDS broadcasts amortized
// over 4 rows -> VALU-bound. rstd/mB precomputed by kG.
__global__ __launch_bounds__(1024) void k4_attn(
    const float* __restrict__ ws,
    const float* __restrict__ ln_g, const float* __restrict__ ln_b,
    const float* __restrict__ attn_bp, float* __restrict__ attnp) {
  const int bid = blockIdx.x;
  const int wg = (bid & 7) * 32 + (bid >> 3);   // one b per XCD
  const int b = wg >> 5;
  const int i0 = (wg & 31) * 4;
  const int t = threadIdx.x;
  const int jl = t & 127;
  const int hg = t >> 7;

  __shared__ float v2s[2048];    // [h][256]
  __shared__ float gbs[512];     // ln_g | ln_b
  __shared__ float p1e[1024];    // [4][256]
  __shared__ float aqs[32];      // [r][h]
  __shared__ float dpart[8192];  // [hg][h][jl]
  __shared__ float redm[16], reds[16];

  const float* P1Tf = ws + WS_P1T;
  const float* AQ = ws + WS_AQ;
  const float* AK = ws + WS_AK;
  const float* BF = ws + WS_BF;
  const float* v2p = ws + WS_V2;
  const float* RST = ws + WS_RSTD + b * N * N;
  const float* MBP = ws + WS_MB + b * N * N;

  for (int k = t; k < 2048; k += 1024) v2s[k] = v2p[k];
  if (t < 512) gbs[t] = (t < 256) ? ln_g[t] : ln_b[t - 256];
  {
    const int r = t >> 8, c = t & 255;
    const int row = i0 + r - 1;
    p1e[r * 256 + c] = (row >= 0)
        ? P1Tf[(b * 64 + (c >> 2)) * 512 + row * 4 + (c & 3)] : 0.f;
  }
  if (t < 32) {
    const int r = t >> 3, h = t & 7;
    aqs[t] = AQ[(b * H + h) * N + i0 + r] + BF[16 + h] + attn_bp[0];
  }

  const int jm1 = (jl == 0) ? 0 : jl - 1;
  const bool blk0 = (i0 == 0);   // row 0 uses per-lane P1[j-1] (cls edge)
  const float4* P14 = reinterpret_cast<const float4*>(ws + WS_P1T);
  const float4* P24 = reinterpret_cast<const float4*>(ws + WS_P2T);
  const int base4 = b * 64 * 128;

  float rstd_[4], mB_[4];
#pragma unroll
  for (int r = 0; r < 4; ++r) {
    const int ip = (blk0 && r == 0) ? jm1 : (i0 + r - 1);
    rstd_[r] = RST[ip * N + jm1];
    mB_[r] = MBP[ip * N + jm1];
  }

  // P2 slice -> 8 float4 registers (my 32 channels)
  F4 pp[8];
#pragma unroll
  for (int cc = 0; cc < 8; ++cc)
    pp[cc].v = P24[base4 + (hg * 8 + cc) * 128 + jm1];

  __syncthreads();

  float dt[4][8];
#pragma unroll
  for (int r = 0; r < 4; ++r)
#pragma unroll
    for (int h = 0; h < 8; ++h) dt[r][h] = 0.f;

#pragma unroll
  for (int cc = 0; cc < 8; ++cc) {
    const int c4 = hg * 8 + cc;
    F4 g4; g4.v = *(const float4*)&gbs[c4 * 4];
    F4 b4; b4.v = *(const float4*)&gbs[256 + c4 * 4];
    float w4[4][4];
#pragma unroll
    for (int r = 0; r < 4; ++r) {
      F4 p1;
      if (blk0 && r == 0) p1.v = P14[base4 + c4 * 128 + jm1];
      else p1.v = *(const float4*)&p1e[r * 256 + c4 * 4];
#pragma unroll
      for (int e = 0; e < 4; ++e) {
        const float u = pp[cc].f[e] + p1.f[e];
        const float zt = fmaf(u, rstd_[r], mB_[r]);
        w4[r][e] = fmaxf(fmaf(zt, g4.f[e], b4.f[e]), 0.f);
      }
    }
#pragma unroll
    for (int h = 0; h < 8; ++h) {
      F4 v2v; v2v.v = *(const float4*)&v2s[h * 256 + c4 * 4];
#pragma unroll
      for (int r = 0; r < 4; ++r) {
        float d0 = fmaf(w4[r][0], v2v.f[0], dt[r][h]);
        float d1 = fmaf(w4[r][1], v2v.f[1], d0);
        float d2 = fmaf(w4[r][2], v2v.f[2], d1);
        dt[r][h] = fmaf(w4[r][3], v2v.f[3], d2);
      }
    }
  }

  // softmax: this thread owns head h = hg, column jl; 4 rows sequentially
  const float akv = AK[(b * H + hg) * N + jl];
  const int w = t >> 6;   // partner wave w^1 covers the other jl-half, same h
#pragma unroll
  for (int r = 0; r < 4; ++r) {
#pragma unroll
    for (int h = 0; h < 8; ++h) dpart[(hg * 8 + h) * 128 + jl] = dt[r][h];
    __syncthreads();
    float dsum = 0.f;
#pragma unroll
    for (int g2 = 0; g2 < 8; ++g2) dsum += dpart[(g2 * 8 + hg) * 128 + jl];
    const int irow = i0 + r;
    const bool masked = (jl == 0) || (jl == irow);
    const float sc = masked ? -INFINITY : (aqs[r * 8 + hg] + akv + dsum);
    float mx = sc;
#pragma unroll
    for (int o = 1; o < 64; o <<= 1) mx = fmaxf(mx, __shfl_xor(mx, o));
    if ((t & 63) == 0) redm[w] = mx;
    __syncthreads();
    const float m = fmaxf(redm[w], redm[w ^ 1]);
    const float pr = expf(sc - m);
    float sm = pr;
#pragma unroll
    for (int o = 1; o < 64; o <<= 1) sm += __shfl_xor(sm, o);
    if ((t & 63) == 0) reds[w] = sm;
    __syncthreads();
    const float at = pr / (reds[w] + reds[w ^ 1]);
    attnp[((b * H + hg) * N + irow) * N + jl] = at;
  }
}

// K5: ctx = attn @ v ; out = ctx @ wo + bo. 4 rows per block, 1024 threads
// (r = t>>8 row, c = t&255 channel). grid 256 (XCD-swizzled).
__global__ __launch_bounds__(1024) void k5_out(
    const float* __restrict__ ws, const float* __restrict__ attnp,
    const float* __restrict__ wo, const float* __restrict__ bo,
    float* __restrict__ outp) {
  const int bid = blockIdx.x;
  const int wg = (bid & 7) * 32 + (bid >> 3);   // bijective; same-b per XCD
  const int b = wg >> 5;
  const int i0 = (wg & 31) * 4;
  const int t = threadIdx.x;
  const int r = t >> 8, c = t & 255;

  __shared__ float attn_sh[4][H][N];
  __shared__ float ctxs[4][260];

  for (int k = t; k < 4 * H * N; k += 1024) {
    const int rr = k >> 10, h = (k >> 7) & 7, j = k & 127;
    attn_sh[rr][h][j] = attnp[((b * H + h) * N + i0 + rr) * N + j];
  }
  __syncthreads();

  const int hh = c >> 5;
  const float* Vb = ws + WS_V + b * N * D + c;
  float acc = 0.f;
  for (int j = 0; j < N; ++j)
    acc = fmaf(attn_sh[r][hh][j], Vb[j * D], acc);
  ctxs[r][c] = acc;
  __syncthreads();

  float o = bo[c];
  for (int c2 = 0; c2 < D; c2 += 4) {
    F4 cx; cx.v = *(const float4*)&ctxs[r][c2];
    o = fmaf(cx.f[0], wo[(c2 + 0) * D + c], o);
    o = fmaf(cx.f[1], wo[(c2 + 1) * D + c], o);
    o = fmaf(cx.f[2], wo[(c2 + 2) * D + c], o);
    o = fmaf(cx.f[3], wo[(c2 + 3) * D + c], o);
  }
  outp[(b * N + i0 + r) * D + c] = o;
}

extern "C" void kernel_launch(void* const* d_in, const int* in_sizes, int n_in,
                              void* d_out, int out_size, void* d_ws, size_t ws_size,
                              hipStream_t stream) {
  (void)in_sizes; (void)n_in; (void)out_size; (void)ws_size;
  const float* desc = (const float*)d_in[0];
  const float* nv   = (const float*)d_in[1];
  const float* wq   = (const float*)d_in[2];
  const float* bq   = (const float*)d_in[3];
  const float* wk   = (const float*)d_in[4];
  const float* bk   = (const float*)d_in[5];
  const float* wv   = (const float*)d_in[6];
  const float* bv   = (const float*)d_in[7];
  const float* ew1  = (const float*)d_in[8];
  const float* eb1  = (const float*)d_in[9];
  const float* ln_g = (const float*)d_in[10];
  const float* ln_b = (const float*)d_in[11];
  const float* ew2  = (const float*)d_in[12];
  const float* eb2  = (const float*)d_in[13];
  const float* aw   = (const float*)d_in[14];
  const float* ab   = (const float*)d_in[15];
  const float* wo   = (const float*)d_in[16];
  const float* bo   = (const float*)d_in[17];

  float* ws   = (float*)d_ws;
  float* outp = (float*)d_out;
  float* attnp = outp + B * N * D;

  k1_fold<<<25, 256, 0, stream>>>(wq, wk, ew2, bq, bk, eb2, aw, ws);
  kA_pre<<<512, 256, 0, stream>>>(desc, ew1, eb1, nv, wv, bv, ws);
  kG_stats<<<256, 512, 0, stream>>>(ws);
  k4_attn<<<256, 1024, 0, stream>>>(ws, ln_g, ln_b, ab, attnp);
  k5_out<<<256, 1024, 0, stream>>>(ws, attnp, wo, bo, outp);
}

// Round 8
// 86.296 us; speedup vs baseline: 3.2705x; 3.2705x over previous
//
#include <hip/hip_runtime.h>
#include <math.h>

namespace {
constexpr int D = 256;
constexpr int H = 8;
constexpr int HD = 32;
constexpr int B = 8;
constexpr int S = 127;
constexpr int N = 128;
constexpr float LN_EPS = 1e-5f;

// ws layout (float offsets). P1T/P2T are stored PACKED:
// element (b, c, i) at (b*64 + (c>>2))*512 + i*4 + (c&3)  -> float4 over c for fixed i.
// P1T rows INCLUDE eb1 (folded at kA time).
constexpr int WS_P1T = 0;                  // B*D*N
constexpr int WS_P2T = WS_P1T + B * D * N; // B*D*N
constexpr int WS_V   = WS_P2T + B * D * N; // B*N*D (row-major)
constexpr int WS_AQ  = WS_V + B * N * D;   // B*H*N
constexpr int WS_AK  = WS_AQ + B * H * N;  // B*H*N
constexpr int WS_FQK = WS_AK + B * H * N;  // D*16 (wq-fold | wk-fold)
constexpr int WS_V2  = WS_FQK + D * 16;    // H*D (transposed: [h][c])
constexpr int WS_BF  = WS_V2 + D * H;      // 32 (bq-fold[8], bk-fold[8], be-fold[8])
constexpr int WS_ST  = WS_BF + 32;         // B*4*N row stats: S1,Q1,S2,Q2 (incl eb1 in P1)
constexpr int WS_RSTD = WS_ST + B * 512;   // B*N*N per-pair 1/std
constexpr int WS_MB   = WS_RSTD + B * N * N; // B*N*N per-pair -mean/std

union F4 { float4 v; float f[4]; };
} // namespace

// K1: fold wq/wk with attn_w[:32]/[32:64] -> FQK (D x 16), ew2 with attn_w[64:96]
// -> V2T (H x D), plus bias folds. Thread-per-output.
__global__ __launch_bounds__(256) void k1_fold(
    const float* __restrict__ wq, const float* __restrict__ wk,
    const float* __restrict__ ew2, const float* __restrict__ bq,
    const float* __restrict__ bk, const float* __restrict__ eb2,
    const float* __restrict__ attn_w, float* __restrict__ ws) {
  float* FQK = ws + WS_FQK;
  float* V2T = ws + WS_V2;
  float* BF  = ws + WS_BF;
  const int tg = blockIdx.x * 256 + threadIdx.x;
  if (tg < 6144) {
    const int mat = tg >> 11;
    const int rem = tg & 2047;
    const int c = rem >> 3;
    const int h = rem & 7;
    const float* W = (mat == 0) ? wq : (mat == 1) ? wk : ew2;
    const float* aw = attn_w + mat * HD;
    const float* wrow = W + c * D + h * HD;
    float s = 0.f;
#pragma unroll
    for (int d = 0; d < HD; ++d) s = fmaf(wrow[d], aw[d], s);
    if (mat < 2) FQK[c * 16 + mat * 8 + h] = s;
    else         V2T[h * D + c] = s;
  } else if (tg < 6168) {
    const int idx = tg - 6144;
    const int mat = idx >> 3;
    const int h = idx & 7;
    const float* bias = (mat == 0) ? bq : (mat == 1) ? bk : eb2;
    const float* aw = attn_w + mat * HD;
    float s = 0.f;
#pragma unroll
    for (int d = 0; d < HD; ++d) s = fmaf(bias[h * HD + d], aw[d], s);
    BF[mat * 8 + h] = s;
  }
}

// KA: role 0 (blocks 0..255): P1/P2 packed-transposed (+eb1 into P1) and the
// per-row stats S1,Q1,S2,Q2. role 1 (blocks 256..511): V rows + aq/ak.
__global__ __launch_bounds__(256) void kA_pre(
    const float* __restrict__ desc, const float* __restrict__ ew1,
    const float* __restrict__ eb1,
    const float* __restrict__ nv, const float* __restrict__ wv,
    const float* __restrict__ bv, float* __restrict__ ws) {
  const int blk = blockIdx.x;
  const int t = threadIdx.x;
  __shared__ float rows[4][264];
  __shared__ float aqred[4][64];
  __shared__ float statred[4][16];

  if (blk < 256) {
    // ---- role 0 ----
    float* P1Tf = ws + WS_P1T;
    float* P2Tf = ws + WS_P2T;
    const int b = blk >> 5;
    const int i0 = (blk & 31) * 4;
    for (int k = t; k < 4 * D; k += 256) {
      const int r = k >> 8, c = k & (D - 1);
      const int row = i0 + r;
      rows[r][c] = (row < S) ? desc[(b * S + row) * D + c] : 0.f;
    }
    __syncthreads();
    float a1[4], a2[4];
#pragma unroll
    for (int ii = 0; ii < 4; ++ii) { a1[ii] = 0.f; a2[ii] = 0.f; }
    for (int c2 = 0; c2 < D; c2 += 4) {
      float w1[4], w2[4];
#pragma unroll
      for (int e = 0; e < 4; ++e) {
        w1[e] = ew1[(c2 + e) * D + t];
        w2[e] = ew1[(D + c2 + e) * D + t];
      }
#pragma unroll
      for (int ii = 0; ii < 4; ++ii) {
        F4 dv; dv.v = *(const float4*)&rows[ii][c2];
#pragma unroll
        for (int e = 0; e < 4; ++e) {
          a1[ii] = fmaf(dv.f[e], w1[e], a1[ii]);
          a2[ii] = fmaf(dv.f[e], w2[e], a2[ii]);
        }
      }
    }
    const float ebv = eb1[t];
    const int pbase = (b * 64 + (t >> 2)) * 512 + (t & 3);
#pragma unroll
    for (int ii = 0; ii < 4; ++ii) {
      if (i0 + ii < S) {
        P1Tf[pbase + (i0 + ii) * 4] = a1[ii] + ebv;
        P2Tf[pbase + (i0 + ii) * 4] = a2[ii];
      }
    }
    // per-row stats (S1,Q1 of p1+eb1; S2,Q2 of p2), reduced over channels
    float stv[16];
#pragma unroll
    for (int ii = 0; ii < 4; ++ii) {
      const float v1 = a1[ii] + ebv;
      const float v2x = a2[ii];
      stv[ii * 4 + 0] = v1;
      stv[ii * 4 + 1] = v1 * v1;
      stv[ii * 4 + 2] = v2x;
      stv[ii * 4 + 3] = v2x * v2x;
    }
#pragma unroll
    for (int st = 0; st < 16; ++st) {
#pragma unroll
      for (int o = 1; o < 64; o <<= 1) stv[st] += __shfl_xor(stv[st], o);
    }
    const int w = t >> 6;
    if ((t & 63) == 0) {
#pragma unroll
      for (int st = 0; st < 16; ++st) statred[w][st] = stv[st];
    }
    __syncthreads();
    if (t < 16) {
      const int ii = t >> 2, st = t & 3;
      if (i0 + ii < S) {
        const float s = statred[0][t] + statred[1][t]
                      + statred[2][t] + statred[3][t];
        ws[WS_ST + b * 512 + st * 128 + (i0 + ii)] = s;
      }
    }
  } else {
    // ---- role 1: v = nv @ wv + bv, aq/ak via folded FQK ----
    float* Vf  = ws + WS_V;
    float* AQ  = ws + WS_AQ;
    float* AK  = ws + WS_AK;
    const float* FQK = ws + WS_FQK;
    const float* BF  = ws + WS_BF;
    const int blk2 = blk - 256;
    const int b = blk2 >> 5;
    const int j0 = (blk2 & 31) * 4;
    for (int k = t; k < 4 * D; k += 256) {
      const int r = k >> 8, c = k & (D - 1);
      rows[r][c] = nv[(b * N + j0 + r) * D + c];
    }
    __syncthreads();
    float acc[4];
#pragma unroll
    for (int jj = 0; jj < 4; ++jj) acc[jj] = 0.f;
    for (int c2 = 0; c2 < D; c2 += 4) {
      float wvv[4];
#pragma unroll
      for (int e = 0; e < 4; ++e) wvv[e] = wv[(c2 + e) * D + t];
#pragma unroll
      for (int jj = 0; jj < 4; ++jj) {
        F4 x; x.v = *(const float4*)&rows[jj][c2];
#pragma unroll
        for (int e = 0; e < 4; ++e) acc[jj] = fmaf(x.f[e], wvv[e], acc[jj]);
      }
    }
    const float bias = bv[t];
#pragma unroll
    for (int jj = 0; jj < 4; ++jj)
      Vf[(b * N + j0 + jj) * D + t] = acc[jj] + bias;

    const int pair = t & 63;        // (row il, output oi)
    const int cq = t >> 6;          // channel quarter
    const int il = pair >> 4, oi = pair & 15;
    float s = 0.f;
    for (int c = cq * 64; c < cq * 64 + 64; ++c)
      s = fmaf(rows[il][c], FQK[c * 16 + oi], s);
    aqred[cq][pair] = s;
    __syncthreads();
    if (t < 64) {
      const int il2 = t >> 4, oi2 = t & 15;
      float s2 = aqred[0][t] + aqred[1][t] + aqred[2][t] + aqred[3][t] + BF[oi2];
      if (oi2 < 8) AQ[(b * H + oi2) * N + j0 + il2] = s2;
      else         AK[(b * H + (oi2 - 8)) * N + j0 + il2] = s2;
    }
  }
}

// KG: G = P1 . P2 per (ip,jp) pair via reg-cached P2 slices, then fold with
// row stats ST into per-pair rstd / mB. grid 256 (XCD-swizzled), 512 threads:
// jp = t&127, cg = t>>7 (64-channel group); 4 ip rows per block.
__global__ __launch_bounds__(512) void kG_stats(float* __restrict__ ws) {
  const int bid = blockIdx.x;
  const int wg = (bid & 7) * 32 + (bid >> 3);   // one b per XCD
  const int b = wg >> 5;
  const int ip0 = (wg & 31) * 4;
  const int t = threadIdx.x;
  const int jp = t & 127;
  const int cg = t >> 7;

  __shared__ float p1t[1024];        // [4][256]
  __shared__ float gred[4][4][128];  // [cg][r][jp]

  const float* P1Tf = ws + WS_P1T;
  const float4* P24 = reinterpret_cast<const float4*>(ws + WS_P2T);
  const float* ST = ws + WS_ST + b * 512;
  float* RST = ws + WS_RSTD + b * N * N;
  float* MBP = ws + WS_MB + b * N * N;
  const int base4 = b * 64 * 128;

  for (int k = t; k < 1024; k += 512) {
    const int r = k >> 8, c = k & 255;
    const int row = ip0 + r;
    p1t[r * 256 + c] = (row < S)
        ? P1Tf[(b * 64 + (c >> 2)) * 512 + row * 4 + (c & 3)] : 0.f;
  }
  F4 pp[16];
#pragma unroll
  for (int cc = 0; cc < 16; ++cc)
    pp[cc].v = P24[base4 + (cg * 16 + cc) * 128 + jp];
  __syncthreads();

  float g[4] = {0.f, 0.f, 0.f, 0.f};
#pragma unroll
  for (int cc = 0; cc < 16; ++cc) {
    const int c4 = cg * 16 + cc;
#pragma unroll
    for (int r = 0; r < 4; ++r) {
      F4 p1; p1.v = *(const float4*)&p1t[r * 256 + c4 * 4];
      g[r] = fmaf(pp[cc].f[0], p1.f[0], g[r]);
      g[r] = fmaf(pp[cc].f[1], p1.f[1], g[r]);
      g[r] = fmaf(pp[cc].f[2], p1.f[2], g[r]);
      g[r] = fmaf(pp[cc].f[3], p1.f[3], g[r]);
    }
  }
#pragma unroll
  for (int r = 0; r < 4; ++r) gred[cg][r][jp] = g[r];
  __syncthreads();
  {
    const int r2 = t >> 7, jp2 = t & 127;
    const float G = gred[0][r2][jp2] + gred[1][r2][jp2]
                  + gred[2][r2][jp2] + gred[3][r2][jp2];
    const int ip = ip0 + r2;
    const float S1 = ST[0 * 128 + ip], Q1 = ST[1 * 128 + ip];
    const float S2 = ST[2 * 128 + jp2], Q2 = ST[3 * 128 + jp2];
    const float mean = (S1 + S2) * (1.f / 256.f);
    const float var = (Q1 + Q2 + 2.f * G) * (1.f / 256.f) - mean * mean;
    const float rstd = 1.f / sqrtf(var + LN_EPS);
    RST[ip * N + jp2] = rstd;
    MBP[ip * N + jp2] = -mean * rstd;
  }
}

// K4: edge-MLP dot (loop B only; LN coeffs precomputed by kG) -> scores ->
// softmax -> attn write. grid B*N (XCD-swizzled), block = one (b,i) row.
// 256 threads: jl = t&127 (column j), cp = t>>7 (channel half for the MLP,
// head half [4cp,4cp+4) for softmax). P2/p1 vector loads from L1/L2;
// v2/ln_g/ln_b uniform (scalar) loads; p1 row via LDS broadcast.
__global__ __launch_bounds__(256) void k4_attn(
    const float* __restrict__ ws,
    const float* __restrict__ ln_g, const float* __restrict__ ln_b,
    const float* __restrict__ attn_bp, float* __restrict__ attnp) {
  const int bid = blockIdx.x;
  const int wg = (bid & 7) * 128 + (bid >> 3);   // bijective; one b per XCD
  const int b = wg >> 7;
  const int i = wg & 127;
  const int t = threadIdx.x;
  const int jl = t & 127;
  const int cp = t >> 7;

  __shared__ float p1e[D];
  __shared__ float dsh[2][128][9];
  __shared__ float aqs[8];
  __shared__ float redm[4][4], reds[4][4];

  const float* P1Tf = ws + WS_P1T;
  const float* AQ   = ws + WS_AQ;
  const float* AK   = ws + WS_AK;
  const float* BF   = ws + WS_BF;
  const float* v2p  = ws + WS_V2;
  const float* RST  = ws + WS_RSTD + b * N * N;
  const float* MBP  = ws + WS_MB + b * N * N;

  p1e[t] = (i >= 1)
      ? P1Tf[(b * 64 + (t >> 2)) * 512 + (i - 1) * 4 + (t & 3)] : 0.f;
  if (t < 8) aqs[t] = AQ[(b * H + t) * N + i] + BF[16 + t] + attn_bp[0];

  const int jm1 = (jl == 0) ? 0 : jl - 1;
  const bool row0 = (i == 0);   // row i==0 uses per-lane P1[j-1] (cls edge)
  const int ip = row0 ? jm1 : (i - 1);
  const float rstd = RST[ip * N + jm1];
  const float mB   = MBP[ip * N + jm1];
  float akr[8];
#pragma unroll
  for (int h = 0; h < 8; ++h) akr[h] = AK[(b * H + h) * N + jl];
  __syncthreads();

  const float4* P14 = reinterpret_cast<const float4*>(ws + WS_P1T);
  const float4* P24 = reinterpret_cast<const float4*>(ws + WS_P2T);
  const int base4 = b * 64 * 128;
  const int c4lo = cp * 32, c4hi = c4lo + 32;

  // loop B: relu(LN(u)) . v2 for 8 heads over this half's 128 channels
  float dt[8];
#pragma unroll
  for (int h = 0; h < 8; ++h) dt[h] = 0.f;
  for (int c4 = c4lo; c4 < c4hi; ++c4) {
    F4 p2; p2.v = P24[base4 + c4 * 128 + jm1];
    F4 p1;
    if (row0) p1.v = P14[base4 + c4 * 128 + jm1];
    else      p1.v = *(const float4*)&p1e[c4 * 4];
    F4 g4; g4.v = *(const float4*)&ln_g[c4 * 4];
    F4 b4; b4.v = *(const float4*)&ln_b[c4 * 4];
    float w4[4];
#pragma unroll
    for (int e = 0; e < 4; ++e) {
      const float u = p1.f[e] + p2.f[e];
      const float zt = fmaf(u, rstd, mB);
      w4[e] = fmaxf(fmaf(zt, g4.f[e], b4.f[e]), 0.f);
    }
#pragma unroll
    for (int h = 0; h < 8; ++h) {
      F4 v2v; v2v.v = *(const float4*)&v2p[h * D + c4 * 4];
      float d0 = fmaf(w4[0], v2v.f[0], dt[h]);
      float d1 = fmaf(w4[1], v2v.f[1], d0);
      float d2 = fmaf(w4[2], v2v.f[2], d1);
      dt[h] = fmaf(w4[3], v2v.f[3], d2);
    }
  }
#pragma unroll
  for (int h = 0; h < 8; ++h) dsh[cp][jl][h] = dt[h];
  __syncthreads();

  // scores + softmax: cp half handles heads [4cp, 4cp+4); all 4 waves busy.
  const int h0 = cp * 4;
  const bool masked = (jl == 0) || (jl == i);
  float sc[4], pr[4];
#pragma unroll
  for (int hh = 0; hh < 4; ++hh) {
    const int h = h0 + hh;
    const float v = aqs[h] + akr[h] + dsh[0][jl][h] + dsh[1][jl][h];
    sc[hh] = masked ? -INFINITY : v;
  }
  const int wv = t >> 6;
  const int wp = wv & 2;  // wave-pair base: {0,1} for cp=0, {2,3} for cp=1
  float mx[4];
#pragma unroll
  for (int hh = 0; hh < 4; ++hh) {
    float v = sc[hh];
#pragma unroll
    for (int o = 1; o < 64; o <<= 1) v = fmaxf(v, __shfl_xor(v, o));
    mx[hh] = v;
  }
  if ((t & 63) == 0) {
#pragma unroll
    for (int hh = 0; hh < 4; ++hh) redm[wv][hh] = mx[hh];
  }
  __syncthreads();
#pragma unroll
  for (int hh = 0; hh < 4; ++hh) {
    const float m = fmaxf(redm[wp][hh], redm[wp + 1][hh]);
    pr[hh] = expf(sc[hh] - m);
  }
  float sm[4];
#pragma unroll
  for (int hh = 0; hh < 4; ++hh) {
    float v = pr[hh];
#pragma unroll
    for (int o = 1; o < 64; o <<= 1) v += __shfl_xor(v, o);
    sm[hh] = v;
  }
  if ((t & 63) == 0) {
#pragma unroll
    for (int hh = 0; hh < 4; ++hh) reds[wv][hh] = sm[hh];
  }
  __syncthreads();
#pragma unroll
  for (int hh = 0; hh < 4; ++hh) {
    const float at = pr[hh] / (reds[wp][hh] + reds[wp + 1][hh]);
    attnp[((b * H + h0 + hh) * N + i) * N + jl] = at;
  }
}

// K5: ctx = attn @ v ; out = ctx @ wo + bo. 4 rows per block, 1024 threads
// (r = t>>8 row, c = t&255 channel). grid 256 (XCD-swizzled).
__global__ __launch_bounds__(1024) void k5_out(
    const float* __restrict__ ws, const float* __restrict__ attnp,
    const float* __restrict__ wo, const float* __restrict__ bo,
    float* __restrict__ outp) {
  const int bid = blockIdx.x;
  const int wg = (bid & 7) * 32 + (bid >> 3);   // bijective; same-b per XCD
  const int b = wg >> 5;
  const int i0 = (wg & 31) * 4;
  const int t = threadIdx.x;
  const int r = t >> 8, c = t & 255;

  __shared__ float attn_sh[4][H][N];
  __shared__ float ctxs[4][260];

  for (int k = t; k < 4 * H * N; k += 1024) {
    const int rr = k >> 10, h = (k >> 7) & 7, j = k & 127;
    attn_sh[rr][h][j] = attnp[((b * H + h) * N + i0 + rr) * N + j];
  }
  __syncthreads();

  const int hh = c >> 5;
  const float* Vb = ws + WS_V + b * N * D + c;
  float acc = 0.f;
  for (int j = 0; j < N; ++j)
    acc = fmaf(attn_sh[r][hh][j], Vb[j * D], acc);
  ctxs[r][c] = acc;
  __syncthreads();

  float o = bo[c];
  for (int c2 = 0; c2 < D; c2 += 4) {
    F4 cx; cx.v = *(const float4*)&ctxs[r][c2];
    o = fmaf(cx.f[0], wo[(c2 + 0) * D + c], o);
    o = fmaf(cx.f[1], wo[(c2 + 1) * D + c], o);
    o = fmaf(cx.f[2], wo[(c2 + 2) * D + c], o);
    o = fmaf(cx.f[3], wo[(c2 + 3) * D + c], o);
  }
  outp[(b * N + i0 + r) * D + c] = o;
}

extern "C" void kernel_launch(void* const* d_in, const int* in_sizes, int n_in,
                              void* d_out, int out_size, void* d_ws, size_t ws_size,
                              hipStream_t stream) {
  (void)in_sizes; (void)n_in; (void)out_size; (void)ws_size;
  const float* desc = (const float*)d_in[0];
  const float* nv   = (const float*)d_in[1];
  const float* wq   = (const float*)d_in[2];
  const float* bq   = (const float*)d_in[3];
  const float* wk   = (const float*)d_in[4];
  const float* bk   = (const float*)d_in[5];
  const float* wv   = (const float*)d_in[6];
  const float* bv   = (const float*)d_in[7];
  const float* ew1  = (const float*)d_in[8];
  const float* eb1  = (const float*)d_in[9];
  const float* ln_g = (const float*)d_in[10];
  const float* ln_b = (const float*)d_in[11];
  const float* ew2  = (const float*)d_in[12];
  const float* eb2  = (const float*)d_in[13];
  const float* aw   = (const float*)d_in[14];
  const float* ab   = (const float*)d_in[15];
  const float* wo   = (const float*)d_in[16];
  const float* bo   = (const float*)d_in[17];

  float* ws   = (float*)d_ws;
  float* outp = (float*)d_out;
  float* attnp = outp + B * N * D;

  k1_fold<<<25, 256, 0, stream>>>(wq, wk, ew2, bq, bk, eb2, aw, ws);
  kA_pre<<<512, 256, 0, stream>>>(desc, ew1, eb1, nv, wv, bv, ws);
  kG_stats<<<256, 512, 0, stream>>>(ws);
  k4_attn<<<B * N, 256, 0, stream>>>(ws, ln_g, ln_b, ab, attnp);
  k5_out<<<256, 1024, 0, stream>>>(ws, attnp, wo, bo, outp);
}